// Round 17
// baseline (4731.958 us; speedup 1.0000x reference)
//
#include <hip/hip_runtime.h>
#include <math.h>

// EncoderRNN persistent kernel, round 22 = round 21 champion (3.90ms) + ONE
// structural change: B-operands FRAGMENT-DIRECT from global (split mode).
// With h as bf16 u16 (r21), hpk[batch][unit] IS the MFMA B-fragment layout:
// lane (n=lane&15, k=kc*32+(lane>>4)*8) -> slab + n*NH + k, one 16B load per
// kc, 64 lanes fully consuming 16 lines/instr (same coalescing as staging,
// SAME total load count: 16 ald64/thread), straight into registers. Deletes
// the stage->LDS-write->__syncthreads->ds_read chain; split mode drops to 3
// barriers/step (gl2 WAR covered by the post-cell drain barrier). L0's emb-x
// fragments prefetch from embP in fragment layout during the poll (tokens
// known a step ahead) -> L0 waves 0-1 enter MFMA immediately after the poll
// join. Values bitwise identical to r21 (same bf16 inputs, same MFMA order)
// -> absmax must stay EXACTLY 0.0001220703 (built-in layout check).
// Fallback (small ws): r21 LDS-staging path verbatim under if(!p.bwd).
// Predicted: pass, absmax 0.0001220703 exact, dur 3.90 -> ~3.4-3.7ms,
// SQ_LDS_BANK_CONFLICT 1.09e8 -> <2e7, FETCH/WRITE unchanged.
// Pre-registered: absmax change => layout bug, revert r21; regression w/
// VGPR>256 or scratch => register pressure, revert r21.

#define SEQ 1024
#define NB 32
#define NH 512
#define BH (NB*NH)
#define NV 32000
#define KP 1032   // LDS row stride in shorts (fallback staging only)

typedef __attribute__((ext_vector_type(8))) short short8;
typedef __attribute__((ext_vector_type(4))) float f32x4;
typedef unsigned long long u64;

struct P {
  const int*   word;
  const float* emb;
  const float* Wih[4];   // dl = dir*2+layer: 0=fwd1,1=fwd2,2=bwd1,3=bwd2
  const float* Whh[4];
  const float* bih[4];
  const float* bhh[4];
  unsigned* flags;       // 256 slots, stride 16 u32 (one 64B line each)
  unsigned* gen;         // single 64B line (fallback 2-hop only)
  unsigned short* hpk;   // [4 dl][2 par][NB][NH] u16 bf16 h (256 KB)
  const unsigned* embP;  // [NV][NH] u32 packed (hh | hl<<16), or null
  float* out;
  float* bwd;            // bwd-direction partial buffer (or null = fallback)
};

__device__ __forceinline__ unsigned short f2bf(float x) {
  unsigned u = __float_as_uint(x);
  return (unsigned short)((u + 0x7fffu + ((u >> 16) & 1u)) >> 16);  // RNE
}
__device__ __forceinline__ float bf2f(unsigned short b) {
  return __uint_as_float(((unsigned)b) << 16);
}
__device__ __forceinline__ float sigf(float x) { return 1.0f / (1.0f + expf(-x)); }

__device__ __forceinline__ unsigned ald(const unsigned* p_) {
  return __hip_atomic_load((unsigned*)p_, __ATOMIC_RELAXED, __HIP_MEMORY_SCOPE_AGENT);
}
__device__ __forceinline__ u64 ald64(const u64* p_) {
  return __hip_atomic_load((u64*)p_, __ATOMIC_RELAXED, __HIP_MEMORY_SCOPE_AGENT);
}
__device__ __forceinline__ void ast(unsigned* p_, unsigned v) {
  __hip_atomic_store(p_, v, __ATOMIC_RELAXED, __HIP_MEMORY_SCOPE_AGENT);
}
__device__ __forceinline__ void ast16(unsigned short* p_, unsigned short v) {
  __hip_atomic_store(p_, v, __ATOMIC_RELAXED, __HIP_MEMORY_SCOPE_AGENT);
}
__device__ __forceinline__ float aldf(const float* p_) {
  return __hip_atomic_load((float*)p_, __ATOMIC_RELAXED, __HIP_MEMORY_SCOPE_AGENT);
}
__device__ __forceinline__ void astf(float* p_, float v) {
  __hip_atomic_store(p_, v, __ATOMIC_RELAXED, __HIP_MEMORY_SCOPE_AGENT);
}

// FALLBACK-ONLY: coalesced bf16 slab stage (r21 path).
__device__ __forceinline__ void stage_slab16(const unsigned short* slab,
                                             unsigned short* xhHi,
                                             int Lpair, int koff) {
  const u64* s64 = (const u64*)slab;
  u64 A[16];
#pragma unroll
  for (int q = 0; q < 16; ++q) A[q] = ald64(s64 + Lpair + q * 128);
#pragma unroll
  for (int q = 0; q < 16; ++q) {
    const int idx = Lpair + q * 128;   // u64 index in [0,2048)
    const int r   = idx >> 7;          // batch row 0..15
    const int uc  = (idx & 127) * 4;   // unit col (4 units per u64)
    *(u64*)(xhHi + r * KP + koff + uc) = A[q];
  }
}

// one-time embedding fp32 -> packed u32 (hh | hl<<16); identical RNE math
__global__ void conv_embp(const float* __restrict__ e,
                          unsigned* __restrict__ pk) {
  const size_t i = ((size_t)blockIdx.x * 256 + threadIdx.x) * 8;
  float4 a = *(const float4*)(e + i);
  float4 b = *(const float4*)(e + i + 4);
  float xs[8] = {a.x, a.y, a.z, a.w, b.x, b.y, b.z, b.w};
  unsigned o[8];
#pragma unroll
  for (int q = 0; q < 8; ++q) {
    unsigned short hb = f2bf(xs[q]);
    unsigned short lb = f2bf(xs[q] - bf2f(hb));
    o[q] = (unsigned)hb | ((unsigned)lb << 16);
  }
  uint4 v0, v1;
  v0.x=o[0]; v0.y=o[1]; v0.z=o[2]; v0.w=o[3];
  v1.x=o[4]; v1.y=o[5]; v1.z=o[6]; v1.w=o[7];
  *(uint4*)(pk + i)     = v0;
  *(uint4*)(pk + i + 4) = v1;
}

// post-pass: out[i] += bwd[i] over SEQ*BH. Two-term fp32 add (commutes).
__global__ void merge_out(float* __restrict__ out, const float* __restrict__ bwd) {
  const size_t i = ((size_t)blockIdx.x * 256 + threadIdx.x) * 4;
  float4 a = *(const float4*)(out + i);
  const float4 b = *(const float4*)(bwd + i);
  a.x += b.x; a.y += b.y; a.z += b.z; a.w += b.w;
  *(float4*)(out + i) = a;
}

__global__ __launch_bounds__(256, 1) void enc_persist(P p) {
  extern __shared__ unsigned short smem[];
  unsigned short* xhHi = smem;              // [16][KP] (fallback only)
  unsigned short* xhLo = smem + 16 * KP;    // [16][KP] (fallback only)
  float* gl2 = (float*)(smem + 32 * KP);    // [4 wv][4 gate][16 batch][20] fp32

  const int tid  = threadIdx.x;
  const int bid  = blockIdx.x;
  const int dl   = bid >> 6;
  const int dir  = dl >> 1, layer = dl & 1;
  const int r6   = bid & 63;
  const int u0   = (r6 >> 1) * 16;   // 32 unit-groups of 16
  const int b0   = (r6 & 1) * 16;    // 2 batch-halves of 16
  const int lane = tid & 63, wv = tid >> 6;   // wave wv owns kc in [8wv, 8wv+8)

  // barrier domain (split mode): (dir, batch-half) = exact dependency closure
  const int dom  = p.bwd ? (dir * 2 + (r6 & 1)) : 0;
  const int lid  = p.bwd ? (layer * 32 + (r6 >> 1)) : bid;

  // B_lo exists only for L0's emb x range (waves 0-1); wave-uniform.
  const bool use_lo = (layer == 0) && (wv < 2);
  // split-mode: L0 waves 0-1 consume prefetched emb fragments from epr
  const bool frag_emb = use_lo && (p.bwd != nullptr) && (p.embP != nullptr);

  // ---- prologue: W fragments (bf16 hi/lo) for all 4 gates, this wave's K ----
  short8 aHi[32], aLo[32];   // index gg*8+kk
  {
    const int kg = (lane >> 4) * 8;
#pragma unroll
    for (int gg = 0; gg < 4; ++gg) {
      const int gr = gg * 512 + u0 + (lane & 15);   // global gate row
      const float* Wi = p.Wih[dl] + (size_t)gr * NH;
      const float* Wh = p.Whh[dl] + (size_t)gr * NH;
#pragma unroll
      for (int kk = 0; kk < 8; ++kk) {
        const int k0 = (wv * 8 + kk) * 32 + kg;
        const float* s = (k0 < 512) ? (Wi + k0) : (Wh + (k0 - 512));
        float4 v0 = *(const float4*)s;
        float4 v1 = *(const float4*)(s + 4);
        float xs[8] = {v0.x, v0.y, v0.z, v0.w, v1.x, v1.y, v1.z, v1.w};
        short8 h8, l8;
#pragma unroll
        for (int q = 0; q < 8; ++q) {
          unsigned short hb = f2bf(xs[q]);
          h8[q] = (short)hb;
          l8[q] = (short)f2bf(xs[q] - bf2f(hb));
        }
        aHi[gg * 8 + kk] = h8; aLo[gg * 8 + kk] = l8;
      }
    }
  }

  // cell thread mapping: cb = batch-local (tid>>4), cu = unit (tid&15)
  const int cu = tid & 15, cb = tid >> 4;
  const int uG = u0 + cu;
  const float bi  = p.bih[dl][uG]        + p.bhh[dl][uG];
  const float bf_ = p.bih[dl][512 + uG]  + p.bhh[dl][512 + uG];
  const float bg  = p.bih[dl][1024 + uG] + p.bhh[dl][1024 + uG];
  const float bo  = p.bih[dl][1536 + uG] + p.bhh[dl][1536 + uG];

  float c_reg = 0.f, h_reg = 0.f;

  // fallback emb staging mapping (embP null): rb = row, sr = k-slice
  const int sr = tid >> 4;
  const int rb = tid & 15;
  const int ks = sr * 64;
  // fallback packed-emb staging mapping: rp = row (tid>>3), lp = tid&7
  const int rp = tid >> 3;
  const int lp = tid & 7;

  // fragment addressing (split mode): n = batch row, kg16 = k sub-offset
  const int n    = lane & 15;
  const int kg16 = (lane >> 4) * 8;

  int tk, tk_st, tk_pk, tk_fr;
  {
    const int to0 = dir ? (SEQ - 1) : 0;
    tk    = p.word[(size_t)to0 * NB + b0 + cb];        // cell mask token
    tk_st = p.word[(size_t)to0 * NB + b0 + rb];        // fallback fp32 staging
    tk_pk = p.word[(size_t)to0 * NB + b0 + (rp & 15)]; // fallback packed staging
    tk_fr = p.word[(size_t)to0 * NB + b0 + n];         // fragment prefetch row
  }

  const bool use_pk = (layer == 0) && (tid < 128) && (p.embP != nullptr) && !p.bwd;
  const bool do_epf = (layer == 0) && (sr < 8) && (p.embP == nullptr);
  union { float4 f[16]; uint4 u[16]; } epr;
  if (frag_emb) {   // prologue fragment prefetch for j=0: kc range [8wv,8wv+8)
    const unsigned* src = p.embP + (size_t)tk_fr * NH + (wv * 8) * 32 + kg16;
#pragma unroll
    for (int q = 0; q < 16; ++q)
      epr.u[q] = *(const uint4*)(src + (q >> 1) * 32 + (q & 1) * 4);
  } else if (use_pk) {   // fallback packed staging prologue
    const uint4* src = (const uint4*)(p.embP + (size_t)tk_pk * NH);
#pragma unroll
    for (int q = 0; q < 16; ++q) epr.u[q] = src[lp + q * 8];
  } else if (do_epf) {   // fallback fp32 prologue
    const float* e = p.emb + (size_t)tk_st * NH + ks;
#pragma unroll
    for (int q = 0; q < 16; ++q) epr.f[q] = *(const float4*)(e + q * 4);
  }

  for (int j = 0; j <= SEQ; ++j) {
    const int act = layer ? (j >= 1) : (j < SEQ);
    const int t = layer ? (j - 1) : j;
    const int torig = dir ? (SEQ - 1 - t) : t;
    const int par = j & 1;

    // deferred out store slots (split mode): issued after the flag store
    float out_v = 0.f;
    float* out_tgt = nullptr;

    // ---- B operands ----
    u64 B64[16];   // split-mode direct h fragments (2 u64 per kc)
    if (p.bwd) {
      if (act && !frag_emb) {
        const unsigned short* slab;
        int kbase;
        if (wv < 2) {   // x half: only L1 lands here (L0 uses frag_emb)
          slab = p.hpk + (size_t)((dl - 1) * 2 + par) * BH + (size_t)b0 * NH;
          kbase = wv * 8;
        } else {        // recurrent half (both layers)
          slab = p.hpk + (size_t)(dl * 2 + par) * BH + (size_t)b0 * NH;
          kbase = (wv - 2) * 8;
        }
#pragma unroll
        for (int kk = 0; kk < 8; ++kk) {
          const unsigned short* a = slab + (size_t)n * NH + (kbase + kk) * 32 + kg16;
          B64[2 * kk]     = ald64((const u64*)a);
          B64[2 * kk + 1] = ald64((const u64*)a + 1);
        }
      }
    } else if (act) {
      // ---- FALLBACK: r21 LDS staging path ----
      if (wv < 2) {
        if (layer == 0) {
          if (p.embP) {
#pragma unroll
            for (int q = 0; q < 16; ++q) {
              const uint4 w = epr.u[q];
              const int u = 4 * (lp + q * 8);
              uint2 hv, lv;
              hv.x = (w.x & 0xffffu) | (w.y << 16);
              hv.y = (w.z & 0xffffu) | (w.w << 16);
              lv.x = (w.x >> 16)     | (w.y & 0xffff0000u);
              lv.y = (w.z >> 16)     | (w.w & 0xffff0000u);
              *(uint2*)(xhHi + rp * KP + u) = hv;
              *(uint2*)(xhLo + rp * KP + u) = lv;
            }
          } else {
#pragma unroll
            for (int h2 = 0; h2 < 2; ++h2) {
#pragma unroll
              for (int q = 0; q < 4; ++q) {
                const float4 va = epr.f[h2 * 8 + 2 * q];
                const float4 vb = epr.f[h2 * 8 + 2 * q + 1];
                float xs[8] = {va.x, va.y, va.z, va.w, vb.x, vb.y, vb.z, vb.w};
                unsigned hw[4], lw[4];
#pragma unroll
                for (int m = 0; m < 4; ++m) {
                  unsigned short ha = f2bf(xs[2*m]);
                  unsigned short hc = f2bf(xs[2*m+1]);
                  unsigned short la = f2bf(xs[2*m]   - bf2f(ha));
                  unsigned short lc = f2bf(xs[2*m+1] - bf2f(hc));
                  hw[m] = (unsigned)ha | ((unsigned)hc << 16);
                  lw[m] = (unsigned)la | ((unsigned)lc << 16);
                }
                uint4 hv, lv;
                hv.x=hw[0]; hv.y=hw[1]; hv.z=hw[2]; hv.w=hw[3];
                lv.x=lw[0]; lv.y=lw[1]; lv.z=lw[2]; lv.w=lw[3];
                *(uint4*)(xhHi + rb * KP + ks + h2 * 32 + q * 8) = hv;
                *(uint4*)(xhLo + rb * KP + ks + h2 * 32 + q * 8) = lv;
              }
            }
          }
        } else {
          const unsigned short* slab = p.hpk + (size_t)((dl - 1) * 2 + par) * BH
                                             + (size_t)b0 * NH;
          stage_slab16(slab, xhHi, tid, 0);
        }
      } else {
        const unsigned short* slab = p.hpk + (size_t)(dl * 2 + par) * BH
                                           + (size_t)b0 * NH;
        stage_slab16(slab, xhHi, tid - 128, 512);
      }
    }

    // prefetch next step's tokens (latency hides under MFMA+cell+barrier)
    int tk_nx = tk, tk_st_nx = tk_st, tk_pk_nx = tk_pk, tk_fr_nx = tk_fr;
    if (j < SEQ) {
      int t_nx = layer ? j : (j + 1);
      if (t_nx > SEQ - 1) t_nx = SEQ - 1;
      const int to_nx = dir ? (SEQ - 1 - t_nx) : t_nx;
      tk_nx    = p.word[(size_t)to_nx * NB + b0 + cb];
      tk_st_nx = p.word[(size_t)to_nx * NB + b0 + rb];
      tk_pk_nx = p.word[(size_t)to_nx * NB + b0 + (rp & 15)];
      tk_fr_nx = p.word[(size_t)to_nx * NB + b0 + n];
    }

    // out-partner prefetch: FALLBACK (RMW) mode only
    float out_pf = 0.f;
    size_t oi = 0;
    int do_add = 0;
    if (act && layer == 1) {
      oi = (size_t)torig * BH + (size_t)(b0 + cb) * NH + uG;
      if (!p.bwd) {
        do_add = dir ? (torig < 512) : (torig > 511);
        if (do_add) out_pf = aldf(p.out + oi);
      }
    }

    // fallback: join staging before LDS reads. Split: no barrier needed
    // (B in registers; gl2 WAR covered by the post-cell drain barrier).
    if (!p.bwd) __syncthreads();

    if (act) {
      // ---- K-split MFMA: wave wv sums kc in [8wv,8wv+8) for all 4 gates ----
      f32x4 aA[4], aBC[4];
#pragma unroll
      for (int gg = 0; gg < 4; ++gg) {
        aA[gg]  = (f32x4){0.f, 0.f, 0.f, 0.f};
        aBC[gg] = (f32x4){0.f, 0.f, 0.f, 0.f};
      }
      const unsigned short* bp = xhHi + (lane & 15) * KP + (lane >> 4) * 8;
      const unsigned short* bq = xhLo + (lane & 15) * KP + (lane >> 4) * 8;
#pragma unroll
      for (int kk = 0; kk < 8; ++kk) {
        const int kc = wv * 8 + kk;
        short8 bH, bL;
        if (p.bwd) {
          if (frag_emb) {
            const uint4 w0 = epr.u[2 * kk], w1 = epr.u[2 * kk + 1];
            const unsigned ww[8] = {w0.x, w0.y, w0.z, w0.w, w1.x, w1.y, w1.z, w1.w};
#pragma unroll
            for (int e = 0; e < 8; ++e) {
              bH[e] = (short)(ww[e] & 0xffffu);
              bL[e] = (short)(ww[e] >> 16);
            }
          } else {
            union { u64 v[2]; short8 s; } cv;
            cv.v[0] = B64[2 * kk]; cv.v[1] = B64[2 * kk + 1];
            bH = cv.s;
          }
        } else {
          bH = *(const short8*)(bp + kc * 32);
          if (use_lo) bL = *(const short8*)(bq + kc * 32);
        }
#pragma unroll
        for (int gg = 0; gg < 4; ++gg) {
          aA[gg]  = __builtin_amdgcn_mfma_f32_16x16x32_bf16(aHi[gg*8+kk], bH, aA[gg],  0, 0, 0);
          aBC[gg] = __builtin_amdgcn_mfma_f32_16x16x32_bf16(aLo[gg*8+kk], bH, aBC[gg], 0, 0, 0);
        }
        if (use_lo) {
#pragma unroll
          for (int gg = 0; gg < 4; ++gg)
            aBC[gg] = __builtin_amdgcn_mfma_f32_16x16x32_bf16(aHi[gg*8+kk], bL, aBC[gg], 0, 0, 0);
        }
      }
      // C/D (m89): col = lane&15 = batch, row = (lane>>4)*4 + reg = unit
#pragma unroll
      for (int gg = 0; gg < 4; ++gg) {
        f32x4 acc = aA[gg] + aBC[gg];
        *(f32x4*)&gl2[((wv * 4 + gg) * 16 + (lane & 15)) * 20 + (lane >> 4) * 4] = acc;
      }
    }
    __syncthreads();

    if (act) {
      // ---- fused cell: tree-sum the 4 waves' K-partials ----
#define GL2(w_,g_) gl2[(((w_) * 4 + (g_)) * 16 + cb) * 20 + cu]
      const float vi = ((GL2(0,0)+GL2(1,0)) + (GL2(2,0)+GL2(3,0))) + bi;
      const float vf = ((GL2(0,1)+GL2(1,1)) + (GL2(2,1)+GL2(3,1))) + bf_;
      const float vg = ((GL2(0,2)+GL2(1,2)) + (GL2(2,2)+GL2(3,2))) + bg;
      const float vo = ((GL2(0,3)+GL2(1,3)) + (GL2(2,3)+GL2(3,3))) + bo;
#undef GL2
      float cn = sigf(vf) * c_reg + sigf(vi) * tanhf(vg);
      float hn = sigf(vo) * tanhf(cn);
      if (tk == 1) { cn = c_reg; hn = h_reg; }
      c_reg = cn; h_reg = hn;
      // bf16-only h exchange: one u16 agent store
      const size_t hix = (size_t)(dl * 2 + (par ^ 1)) * BH + (size_t)(b0 + cb) * NH + uG;
      ast16(p.hpk + hix, f2bf(hn));
      if (layer == 1) {
        if (p.bwd) {
          out_v = dir ? (0.5f * hn) : hn;
          out_tgt = (dir ? p.bwd : p.out) + oi;
        } else {
          const float v = dir ? (0.5f * hn) : hn;
          astf(p.out + oi, do_add ? (out_pf + v) : v);
        }
      }
    }

    tk = tk_nx; tk_st = tk_st_nx; tk_pk = tk_pk_nx; tk_fr = tk_fr_nx;

    // ---- device barrier ----
    __syncthreads();   // drains vmcnt -> hpk stores acked at coherence point
    if (tid == 0)
      ast(p.flags + (size_t)(dom * 64 + lid) * 16, (unsigned)(j + 1));

    // deferred out/bwd store: overlaps the poll wait, skips the drain
    if (out_tgt) astf(out_tgt, out_v);

    // issue next-step emb loads NOW; they fly during the poll
    if (j + 1 < SEQ) {
      if (frag_emb) {
        const unsigned* src = p.embP + (size_t)tk_fr * NH + (wv * 8) * 32 + kg16;
#pragma unroll
        for (int q = 0; q < 16; ++q)
          epr.u[q] = *(const uint4*)(src + (q >> 1) * 32 + (q & 1) * 4);
      } else if (use_pk) {
        const uint4* src = (const uint4*)(p.embP + (size_t)tk_pk * NH);
#pragma unroll
        for (int q = 0; q < 16; ++q) epr.u[q] = src[lp + q * 8];
      } else if (do_epf) {
        const float* e = p.emb + (size_t)tk_st * NH + ks;
#pragma unroll
        for (int q = 0; q < 16; ++q) epr.f[q] = *(const float4*)(e + q * 4);
      }
    }

    if (p.bwd) {
      // 1-hop all-poll: 64 single-writer lines (1W/63P class, proven)
      if (tid < 64) {
        unsigned* f = p.flags + (size_t)(dom * 64 + tid) * 16;
        while (ald(f) < (unsigned)(j + 1)) __builtin_amdgcn_s_sleep(1);
      }
      __syncthreads();
    } else {
      // fallback: r6 2-hop leader barrier over 256 blocks
      if (bid == 0) {
        unsigned* f = p.flags + (size_t)tid * 16;
        while (ald(f) < (unsigned)(j + 1)) __builtin_amdgcn_s_sleep(1);
        __syncthreads();
        if (tid == 0) ast(p.gen, (unsigned)(j + 1));
      } else {
        if (tid < 64) {
          while (ald(p.gen) < (unsigned)(j + 1)) __builtin_amdgcn_s_sleep(1);
        }
        __syncthreads();
      }
    }
  }

  // ---- epilogue: backward final carries bh1,bc1,bh2,bc2 ----
  if (dl == 2) {
    p.out[(size_t)SEQ * BH + 0 * (size_t)BH + (size_t)(b0 + cb) * NH + uG] = h_reg;
    p.out[(size_t)SEQ * BH + 1 * (size_t)BH + (size_t)(b0 + cb) * NH + uG] = c_reg;
  } else if (dl == 3) {
    p.out[(size_t)SEQ * BH + 2 * (size_t)BH + (size_t)(b0 + cb) * NH + uG] = h_reg;
    p.out[(size_t)SEQ * BH + 3 * (size_t)BH + (size_t)(b0 + cb) * NH + uG] = c_reg;
  }
}

extern "C" void kernel_launch(void* const* d_in, const int* in_sizes, int n_in,
                              void* d_out, int out_size, void* d_ws, size_t ws_size,
                              hipStream_t stream) {
  P p;
  p.word = (const int*)d_in[0];
  p.emb  = (const float*)d_in[1];
  for (int i = 0; i < 4; ++i) {
    p.Wih[i] = (const float*)d_in[2 + i * 4 + 0];
    p.Whh[i] = (const float*)d_in[2 + i * 4 + 1];
    p.bih[i] = (const float*)d_in[2 + i * 4 + 2];
    p.bhh[i] = (const float*)d_in[2 + i * 4 + 3];
  }
  unsigned char* ws = (unsigned char*)d_ws;
  p.flags = (unsigned*)ws;                        // 16 KB (256 x 64B slots)
  p.gen   = (unsigned*)(ws + 16384);              // 64B (fallback only)
  p.hpk   = (unsigned short*)(ws + 16896);        // 256 KB bf16 h
  const size_t embOff   = (size_t)1 << 20;        // 1 MB
  const size_t embBytes = (size_t)NV * NH * 4;    // 62.5 MB packed table
  p.embP = (ws_size >= embOff + embBytes) ? (const unsigned*)(ws + embOff)
                                          : nullptr;
  const size_t bwdOff   = (size_t)65 << 20;       // 65 MB
  const size_t bwdBytes = (size_t)SEQ * BH * 4;   // 64 MB
  const bool split = (ws_size >= bwdOff + bwdBytes) && (p.embP != nullptr);
  p.bwd = split ? (float*)(ws + bwdOff) : nullptr;
  p.out = (float*)d_out;

  // zero flags + gen + bf16 h (256 KB)
  hipMemsetAsync(d_ws, 0, 16896 + (size_t)8 * BH * 2, stream);

  if (p.embP) {
    // NV*NH = 16,384,000 elems, 8/thread -> 8000 blocks x 256
    hipLaunchKernelGGL(conv_embp, dim3(8000), dim3(256), 0, stream,
                       p.emb, (unsigned*)p.embP);
  }

  // LDS used in split mode is only gl2, but keep the 88KB request to force
  // 1 block/CU (grid 256 = CU count; prevents 2-on-1 skew).
  const int smem = 90112;
  hipFuncSetAttribute(reinterpret_cast<const void*>(enc_persist),
                      hipFuncAttributeMaxDynamicSharedMemorySize, smem);
  hipLaunchKernelGGL(enc_persist, dim3(256), dim3(256), smem, stream, p);

  if (split) {
    // out[i] += bwd[i] over SEQ*BH = 16,777,216 floats = 4 per thread
    hipLaunchKernelGGL(merge_out, dim3(16384), dim3(256), 0, stream,
                       p.out, p.bwd);
  }
}

// Round 18
// 3897.502 us; speedup vs baseline: 1.2141x; 1.2141x over previous
//
#include <hip/hip_runtime.h>
#include <math.h>

// EncoderRNN persistent kernel, round 23 = round 21 champion RESTORED (3.90ms).
// r22's fragment-direct B (lane stride = NH*2 = 1KB) violated the r13
// coalescing law: 64 distinct lines per 16B-load instr, 16B consumed each
// (4x over-fetch, uncoalesced sc1) -> 4.73ms despite bank-conflict dropping
// 1.09e8 -> 3.4e7. Third confirmation that COHERENCE-POINT TRANSACTION COUNT
// governs this kernel (r13 win, r15/16(B) regression, r22 regression).
// Design space now fully mapped: sync protocol (r17/18/19), barrier topology
// (r10/11/15), staging coalescing (r13/22), LDS banking (r6), conversion
// placement (r9/14), byte volume (r21). Session: 13.3 -> 3.90ms (3.4x);
// step ~3.8us vs ~3.3-3.6us model floor for this decomposition.
// Predicted: pass, absmax 0.0001220703, dur ~3.90ms, FETCH ~602MB,
// MfmaUtil ~12.5, VALUBusy ~19.9, bank-conflict ~1.09e8.

#define SEQ 1024
#define NB 32
#define NH 512
#define BH (NB*NH)
#define NV 32000
#define KP 1032   // LDS row stride in shorts = 2064 B (odd 16B slots)

typedef __attribute__((ext_vector_type(8))) short short8;
typedef __attribute__((ext_vector_type(4))) float f32x4;
typedef unsigned long long u64;

struct P {
  const int*   word;
  const float* emb;
  const float* Wih[4];   // dl = dir*2+layer: 0=fwd1,1=fwd2,2=bwd1,3=bwd2
  const float* Whh[4];
  const float* bih[4];
  const float* bhh[4];
  unsigned* flags;       // 256 slots, stride 16 u32 (one 64B line each)
  unsigned* gen;         // single 64B line (fallback 2-hop only)
  unsigned short* hpk;   // [4 dl][2 par][NB][NH] u16 bf16 h (256 KB)
  const unsigned* embP;  // [NV][NH] u32 packed (hh | hl<<16), or null
  float* out;
  float* bwd;            // bwd-direction partial buffer (or null = fallback)
};

__device__ __forceinline__ unsigned short f2bf(float x) {
  unsigned u = __float_as_uint(x);
  return (unsigned short)((u + 0x7fffu + ((u >> 16) & 1u)) >> 16);  // RNE
}
__device__ __forceinline__ float bf2f(unsigned short b) {
  return __uint_as_float(((unsigned)b) << 16);
}
__device__ __forceinline__ float sigf(float x) { return 1.0f / (1.0f + expf(-x)); }

__device__ __forceinline__ unsigned ald(const unsigned* p_) {
  return __hip_atomic_load((unsigned*)p_, __ATOMIC_RELAXED, __HIP_MEMORY_SCOPE_AGENT);
}
__device__ __forceinline__ u64 ald64(const u64* p_) {
  return __hip_atomic_load((u64*)p_, __ATOMIC_RELAXED, __HIP_MEMORY_SCOPE_AGENT);
}
__device__ __forceinline__ void ast(unsigned* p_, unsigned v) {
  __hip_atomic_store(p_, v, __ATOMIC_RELAXED, __HIP_MEMORY_SCOPE_AGENT);
}
__device__ __forceinline__ void ast16(unsigned short* p_, unsigned short v) {
  __hip_atomic_store(p_, v, __ATOMIC_RELAXED, __HIP_MEMORY_SCOPE_AGENT);
}
__device__ __forceinline__ float aldf(const float* p_) {
  return __hip_atomic_load((float*)p_, __ATOMIC_RELAXED, __HIP_MEMORY_SCOPE_AGENT);
}
__device__ __forceinline__ void astf(float* p_, float v) {
  __hip_atomic_store(p_, v, __ATOMIC_RELAXED, __HIP_MEMORY_SCOPE_AGENT);
}

// Coalesced bf16 slab stage: wave-PAIR (128 lanes) reads a 16KB contiguous
// slab (16 rows x 512 bf16) -> hi plane in LDS at [koff,+512). Per instr q:
// 128 lanes cover one full 1KB row; 64 consecutive u64/wave = 8 full lines.
__device__ __forceinline__ void stage_slab16(const unsigned short* slab,
                                             unsigned short* xhHi,
                                             int Lpair, int koff) {
  const u64* s64 = (const u64*)slab;
  u64 A[16];
#pragma unroll
  for (int q = 0; q < 16; ++q) A[q] = ald64(s64 + Lpair + q * 128);
#pragma unroll
  for (int q = 0; q < 16; ++q) {
    const int idx = Lpair + q * 128;   // u64 index in [0,2048)
    const int r   = idx >> 7;          // batch row 0..15
    const int uc  = (idx & 127) * 4;   // unit col (4 units per u64)
    *(u64*)(xhHi + r * KP + koff + uc) = A[q];
  }
}

// one-time embedding fp32 -> packed u32 (hh | hl<<16); identical RNE math
__global__ void conv_embp(const float* __restrict__ e,
                          unsigned* __restrict__ pk) {
  const size_t i = ((size_t)blockIdx.x * 256 + threadIdx.x) * 8;
  float4 a = *(const float4*)(e + i);
  float4 b = *(const float4*)(e + i + 4);
  float xs[8] = {a.x, a.y, a.z, a.w, b.x, b.y, b.z, b.w};
  unsigned o[8];
#pragma unroll
  for (int q = 0; q < 8; ++q) {
    unsigned short hb = f2bf(xs[q]);
    unsigned short lb = f2bf(xs[q] - bf2f(hb));
    o[q] = (unsigned)hb | ((unsigned)lb << 16);
  }
  uint4 v0, v1;
  v0.x=o[0]; v0.y=o[1]; v0.z=o[2]; v0.w=o[3];
  v1.x=o[4]; v1.y=o[5]; v1.z=o[6]; v1.w=o[7];
  *(uint4*)(pk + i)     = v0;
  *(uint4*)(pk + i + 4) = v1;
}

// post-pass: out[i] += bwd[i] over SEQ*BH. Two-term fp32 add (commutes).
__global__ void merge_out(float* __restrict__ out, const float* __restrict__ bwd) {
  const size_t i = ((size_t)blockIdx.x * 256 + threadIdx.x) * 4;
  float4 a = *(const float4*)(out + i);
  const float4 b = *(const float4*)(bwd + i);
  a.x += b.x; a.y += b.y; a.z += b.z; a.w += b.w;
  *(float4*)(out + i) = a;
}

__global__ __launch_bounds__(256, 1) void enc_persist(P p) {
  extern __shared__ unsigned short smem[];
  unsigned short* xhHi = smem;              // [16][KP]
  unsigned short* xhLo = smem + 16 * KP;    // [16][KP] (L0 emb x only)
  float* gl2 = (float*)(smem + 32 * KP);    // [4 wv][4 gate][16 batch][20] fp32

  const int tid  = threadIdx.x;
  const int bid  = blockIdx.x;
  const int dl   = bid >> 6;
  const int dir  = dl >> 1, layer = dl & 1;
  const int r6   = bid & 63;
  const int u0   = (r6 >> 1) * 16;   // 32 unit-groups of 16
  const int b0   = (r6 & 1) * 16;    // 2 batch-halves of 16
  const int lane = tid & 63, wv = tid >> 6;   // wave wv owns kc in [8wv, 8wv+8)

  // barrier domain (split mode): (dir, batch-half) = exact dependency closure
  const int dom  = p.bwd ? (dir * 2 + (r6 & 1)) : 0;
  const int lid  = p.bwd ? (layer * 32 + (r6 >> 1)) : bid;

  // B_lo exists only for L0's emb x range (waves 0-1); wave-uniform.
  const bool use_lo = (layer == 0) && (wv < 2);

  // ---- prologue: W fragments (bf16 hi/lo) for all 4 gates, this wave's K ----
  short8 aHi[32], aLo[32];   // index gg*8+kk
  {
    const int kg = (lane >> 4) * 8;
#pragma unroll
    for (int gg = 0; gg < 4; ++gg) {
      const int gr = gg * 512 + u0 + (lane & 15);   // global gate row
      const float* Wi = p.Wih[dl] + (size_t)gr * NH;
      const float* Wh = p.Whh[dl] + (size_t)gr * NH;
#pragma unroll
      for (int kk = 0; kk < 8; ++kk) {
        const int k0 = (wv * 8 + kk) * 32 + kg;
        const float* s = (k0 < 512) ? (Wi + k0) : (Wh + (k0 - 512));
        float4 v0 = *(const float4*)s;
        float4 v1 = *(const float4*)(s + 4);
        float xs[8] = {v0.x, v0.y, v0.z, v0.w, v1.x, v1.y, v1.z, v1.w};
        short8 h8, l8;
#pragma unroll
        for (int q = 0; q < 8; ++q) {
          unsigned short hb = f2bf(xs[q]);
          h8[q] = (short)hb;
          l8[q] = (short)f2bf(xs[q] - bf2f(hb));
        }
        aHi[gg * 8 + kk] = h8; aLo[gg * 8 + kk] = l8;
      }
    }
  }

  // cell thread mapping: cb = batch-local (tid>>4), cu = unit (tid&15)
  const int cu = tid & 15, cb = tid >> 4;
  const int uG = u0 + cu;
  const float bi  = p.bih[dl][uG]        + p.bhh[dl][uG];
  const float bf_ = p.bih[dl][512 + uG]  + p.bhh[dl][512 + uG];
  const float bg  = p.bih[dl][1024 + uG] + p.bhh[dl][1024 + uG];
  const float bo  = p.bih[dl][1536 + uG] + p.bhh[dl][1536 + uG];

  float c_reg = 0.f, h_reg = 0.f;

  // fallback emb staging mapping (embP null): rb = row, sr = k-slice
  const int sr = tid >> 4;
  const int rb = tid & 15;
  const int ks = sr * 64;

  // packed emb staging mapping (waves 0-1): rp = row (tid>>3), lp = tid&7
  const int rp = tid >> 3;     // 0..15 for tid<128
  const int lp = tid & 7;

  int tk, tk_st, tk_pk;
  {
    const int to0 = dir ? (SEQ - 1) : 0;
    tk    = p.word[(size_t)to0 * NB + b0 + cb];   // cell mask token
    tk_st = p.word[(size_t)to0 * NB + b0 + rb];   // fallback staging token
    tk_pk = p.word[(size_t)to0 * NB + b0 + (rp & 15)]; // packed staging token
  }

  const bool use_pk = (layer == 0) && (tid < 128) && (p.embP != nullptr);
  const bool do_epf = (layer == 0) && (sr < 8) && (p.embP == nullptr);
  union { float4 f[16]; uint4 u[16]; } epr;
  if (use_pk) {   // prologue prefetch for j=0 (packed)
    const uint4* src = (const uint4*)(p.embP + (size_t)tk_pk * NH);
#pragma unroll
    for (int q = 0; q < 16; ++q) epr.u[q] = src[lp + q * 8];
  } else if (do_epf) {  // prologue prefetch for j=0 (fallback fp32)
    const float* e = p.emb + (size_t)tk_st * NH + ks;
#pragma unroll
    for (int q = 0; q < 16; ++q) epr.f[q] = *(const float4*)(e + q * 4);
  }

  for (int j = 0; j <= SEQ; ++j) {
    const int act = layer ? (j >= 1) : (j < SEQ);
    const int t = layer ? (j - 1) : j;
    const int torig = dir ? (SEQ - 1 - t) : t;
    const int par = j & 1;

    // deferred out store slots (split mode): issued after the flag store
    float out_v = 0.f;
    float* out_tgt = nullptr;

    if (act) {
      // ---- stage one row-slice of [x(512);h(512)] into LDS ----
      if (wv < 2) {   // x-part, k in [0,512)  (wave-pair 0, uniform)
        if (layer == 0) {
          if (p.embP) {
            // unpack prefetched packed-emb registers -> LDS (bit-exact)
#pragma unroll
            for (int q = 0; q < 16; ++q) {
              const uint4 w = epr.u[q];
              const int u = 4 * (lp + q * 8);   // unit 0..508
              uint2 hv, lv;
              hv.x = (w.x & 0xffffu) | (w.y << 16);
              hv.y = (w.z & 0xffffu) | (w.w << 16);
              lv.x = (w.x >> 16)     | (w.y & 0xffff0000u);
              lv.y = (w.z >> 16)     | (w.w & 0xffff0000u);
              *(uint2*)(xhHi + rp * KP + u) = hv;
              *(uint2*)(xhLo + rp * KP + u) = lv;
            }
          } else {  // fallback: convert prefetched fp32 regs
#pragma unroll
            for (int h2 = 0; h2 < 2; ++h2) {
#pragma unroll
              for (int q = 0; q < 4; ++q) {
                const float4 va = epr.f[h2 * 8 + 2 * q];
                const float4 vb = epr.f[h2 * 8 + 2 * q + 1];
                float xs[8] = {va.x, va.y, va.z, va.w, vb.x, vb.y, vb.z, vb.w};
                unsigned hw[4], lw[4];
#pragma unroll
                for (int m = 0; m < 4; ++m) {
                  unsigned short ha = f2bf(xs[2*m]);
                  unsigned short hc = f2bf(xs[2*m+1]);
                  unsigned short la = f2bf(xs[2*m]   - bf2f(ha));
                  unsigned short lc = f2bf(xs[2*m+1] - bf2f(hc));
                  hw[m] = (unsigned)ha | ((unsigned)hc << 16);
                  lw[m] = (unsigned)la | ((unsigned)lc << 16);
                }
                uint4 hv, lv;
                hv.x=hw[0]; hv.y=hw[1]; hv.z=hw[2]; hv.w=hw[3];
                lv.x=lw[0]; lv.y=lw[1]; lv.z=lw[2]; lv.w=lw[3];
                *(uint4*)(xhHi + rb * KP + ks + h2 * 32 + q * 8) = hv;
                *(uint4*)(xhLo + rb * KP + ks + h2 * 32 + q * 8) = lv;
              }
            }
          }
        } else {      // layer2 x = layer1 h: coalesced 16KB bf16 slab read
          const unsigned short* slab = p.hpk + (size_t)((dl - 1) * 2 + par) * BH
                                             + (size_t)b0 * NH;
          stage_slab16(slab, xhHi, tid, 0);
        }
      } else {        // recurrent half, k in [512,1024)  (wave-pair 1, uniform)
        const unsigned short* slab = p.hpk + (size_t)(dl * 2 + par) * BH
                                           + (size_t)b0 * NH;
        stage_slab16(slab, xhHi, tid - 128, 512);
      }
    }

    // prefetch next step's tokens (latency hides under MFMA+cell+barrier)
    int tk_nx = tk, tk_st_nx = tk_st, tk_pk_nx = tk_pk;
    if (j < SEQ) {
      int t_nx = layer ? j : (j + 1);
      if (t_nx > SEQ - 1) t_nx = SEQ - 1;
      const int to_nx = dir ? (SEQ - 1 - t_nx) : t_nx;
      tk_nx    = p.word[(size_t)to_nx * NB + b0 + cb];
      tk_st_nx = p.word[(size_t)to_nx * NB + b0 + rb];
      tk_pk_nx = p.word[(size_t)to_nx * NB + b0 + (rp & 15)];
    }

    // out-partner prefetch: FALLBACK (RMW) mode only; split mode never reads out
    float out_pf = 0.f;
    size_t oi = 0;
    int do_add = 0;
    if (act && layer == 1) {
      oi = (size_t)torig * BH + (size_t)(b0 + cb) * NH + uG;
      if (!p.bwd) {
        do_add = dir ? (torig < 512) : (torig > 511);
        if (do_add) out_pf = aldf(p.out + oi);
      }
    }

    __syncthreads();

    if (act) {
      // ---- K-split MFMA: wave wv sums kc in [8wv,8wv+8) for all 4 gates.
      // 3-term (hi*hi, lo*hi, hi*lo) only where B_lo exists (L0 emb x);
      // 2-term elsewhere (h-sourced B has no lo plane).
      f32x4 aA[4], aBC[4];
#pragma unroll
      for (int gg = 0; gg < 4; ++gg) {
        aA[gg]  = (f32x4){0.f, 0.f, 0.f, 0.f};
        aBC[gg] = (f32x4){0.f, 0.f, 0.f, 0.f};
      }
      const unsigned short* bp = xhHi + (lane & 15) * KP + (lane >> 4) * 8;
      const unsigned short* bq = xhLo + (lane & 15) * KP + (lane >> 4) * 8;
#pragma unroll
      for (int kk = 0; kk < 8; ++kk) {
        const int kc = wv * 8 + kk;
        short8 bH = *(const short8*)(bp + kc * 32);
#pragma unroll
        for (int gg = 0; gg < 4; ++gg) {
          aA[gg]  = __builtin_amdgcn_mfma_f32_16x16x32_bf16(aHi[gg*8+kk], bH, aA[gg],  0, 0, 0);
          aBC[gg] = __builtin_amdgcn_mfma_f32_16x16x32_bf16(aLo[gg*8+kk], bH, aBC[gg], 0, 0, 0);
        }
        if (use_lo) {
          short8 bL = *(const short8*)(bq + kc * 32);
#pragma unroll
          for (int gg = 0; gg < 4; ++gg)
            aBC[gg] = __builtin_amdgcn_mfma_f32_16x16x32_bf16(aHi[gg*8+kk], bL, aBC[gg], 0, 0, 0);
        }
      }
      // C/D (m89): col = lane&15 = batch, row = (lane>>4)*4 + reg = unit
#pragma unroll
      for (int gg = 0; gg < 4; ++gg) {
        f32x4 acc = aA[gg] + aBC[gg];
        *(f32x4*)&gl2[((wv * 4 + gg) * 16 + (lane & 15)) * 20 + (lane >> 4) * 4] = acc;
      }
    }
    __syncthreads();

    if (act) {
      // ---- fused cell: tree-sum the 4 waves' K-partials ----
#define GL2(w_,g_) gl2[(((w_) * 4 + (g_)) * 16 + cb) * 20 + cu]
      const float vi = ((GL2(0,0)+GL2(1,0)) + (GL2(2,0)+GL2(3,0))) + bi;
      const float vf = ((GL2(0,1)+GL2(1,1)) + (GL2(2,1)+GL2(3,1))) + bf_;
      const float vg = ((GL2(0,2)+GL2(1,2)) + (GL2(2,2)+GL2(3,2))) + bg;
      const float vo = ((GL2(0,3)+GL2(1,3)) + (GL2(2,3)+GL2(3,3))) + bo;
#undef GL2
      float cn = sigf(vf) * c_reg + sigf(vi) * tanhf(vg);
      float hn = sigf(vo) * tanhf(cn);
      if (tk == 1) { cn = c_reg; hn = h_reg; }
      c_reg = cn; h_reg = hn;
      // bf16-only h exchange: one u16 agent store
      const size_t hix = (size_t)(dl * 2 + (par ^ 1)) * BH + (size_t)(b0 + cb) * NH + uG;
      ast16(p.hpk + hix, f2bf(hn));
      if (layer == 1) {
        if (p.bwd) {
          // split mode: defer store past the flag (no in-kernel reader)
          out_v = dir ? (0.5f * hn) : hn;
          out_tgt = (dir ? p.bwd : p.out) + oi;
        } else {
          // fallback: ordered by the full device barrier; partner prefetched
          const float v = dir ? (0.5f * hn) : hn;
          astf(p.out + oi, do_add ? (out_pf + v) : v);
        }
      }
    }

    tk = tk_nx; tk_st = tk_st_nx; tk_pk = tk_pk_nx;

    // ---- device barrier ----
    __syncthreads();   // drains vmcnt -> hpk stores acked at coherence point
    if (tid == 0)
      ast(p.flags + (size_t)(dom * 64 + lid) * 16, (unsigned)(j + 1));

    // deferred out/bwd store: overlaps the poll wait, skips the drain
    if (out_tgt) astf(out_tgt, out_v);

    // issue next-step emb loads NOW; they fly during the poll
    if (j + 1 < SEQ) {
      if (use_pk) {
        const uint4* src = (const uint4*)(p.embP + (size_t)tk_pk * NH);
#pragma unroll
        for (int q = 0; q < 16; ++q) epr.u[q] = src[lp + q * 8];
      } else if (do_epf) {
        const float* e = p.emb + (size_t)tk_st * NH + ks;
#pragma unroll
        for (int q = 0; q < 16; ++q) epr.f[q] = *(const float4*)(e + q * 4);
      }
    }

    if (p.bwd) {
      // 1-hop all-poll: 64 single-writer lines (1W/63P class, proven)
      if (tid < 64) {
        unsigned* f = p.flags + (size_t)(dom * 64 + tid) * 16;
        while (ald(f) < (unsigned)(j + 1)) __builtin_amdgcn_s_sleep(1);
      }
      __syncthreads();
    } else {
      // fallback: r6 2-hop leader barrier over 256 blocks
      if (bid == 0) {
        unsigned* f = p.flags + (size_t)tid * 16;
        while (ald(f) < (unsigned)(j + 1)) __builtin_amdgcn_s_sleep(1);
        __syncthreads();
        if (tid == 0) ast(p.gen, (unsigned)(j + 1));
      } else {
        if (tid < 64) {
          while (ald(p.gen) < (unsigned)(j + 1)) __builtin_amdgcn_s_sleep(1);
        }
        __syncthreads();
      }
    }
  }

  // ---- epilogue: backward final carries bh1,bc1,bh2,bc2 ----
  if (dl == 2) {
    p.out[(size_t)SEQ * BH + 0 * (size_t)BH + (size_t)(b0 + cb) * NH + uG] = h_reg;
    p.out[(size_t)SEQ * BH + 1 * (size_t)BH + (size_t)(b0 + cb) * NH + uG] = c_reg;
  } else if (dl == 3) {
    p.out[(size_t)SEQ * BH + 2 * (size_t)BH + (size_t)(b0 + cb) * NH + uG] = h_reg;
    p.out[(size_t)SEQ * BH + 3 * (size_t)BH + (size_t)(b0 + cb) * NH + uG] = c_reg;
  }
}

extern "C" void kernel_launch(void* const* d_in, const int* in_sizes, int n_in,
                              void* d_out, int out_size, void* d_ws, size_t ws_size,
                              hipStream_t stream) {
  P p;
  p.word = (const int*)d_in[0];
  p.emb  = (const float*)d_in[1];
  for (int i = 0; i < 4; ++i) {
    p.Wih[i] = (const float*)d_in[2 + i * 4 + 0];
    p.Whh[i] = (const float*)d_in[2 + i * 4 + 1];
    p.bih[i] = (const float*)d_in[2 + i * 4 + 2];
    p.bhh[i] = (const float*)d_in[2 + i * 4 + 3];
  }
  unsigned char* ws = (unsigned char*)d_ws;
  p.flags = (unsigned*)ws;                        // 16 KB (256 x 64B slots)
  p.gen   = (unsigned*)(ws + 16384);              // 64B (fallback only)
  p.hpk   = (unsigned short*)(ws + 16896);        // 256 KB bf16 h
  const size_t embOff   = (size_t)1 << 20;        // 1 MB
  const size_t embBytes = (size_t)NV * NH * 4;    // 62.5 MB packed table
  p.embP = (ws_size >= embOff + embBytes) ? (const unsigned*)(ws + embOff)
                                          : nullptr;
  const size_t bwdOff   = (size_t)65 << 20;       // 65 MB
  const size_t bwdBytes = (size_t)SEQ * BH * 4;   // 64 MB
  const bool split = (ws_size >= bwdOff + bwdBytes) && (p.embP != nullptr);
  p.bwd = split ? (float*)(ws + bwdOff) : nullptr;
  p.out = (float*)d_out;

  // zero flags + gen + bf16 h (256 KB)
  hipMemsetAsync(d_ws, 0, 16896 + (size_t)8 * BH * 2, stream);

  if (p.embP) {
    // NV*NH = 16,384,000 elems, 8/thread -> 8000 blocks x 256
    hipLaunchKernelGGL(conv_embp, dim3(8000), dim3(256), 0, stream,
                       p.emb, (unsigned*)p.embP);
  }

  // used: 32*KP*2 + 4*4*16*20*4 = 86528 B; request 88 KB to keep 1 block/CU
  const int smem = 90112;
  hipFuncSetAttribute(reinterpret_cast<const void*>(enc_persist),
                      hipFuncAttributeMaxDynamicSharedMemorySize, smem);
  hipLaunchKernelGGL(enc_persist, dim3(256), dim3(256), smem, stream, p);

  if (split) {
    // out[i] += bwd[i] over SEQ*BH = 16,777,216 floats = 4 per thread
    hipLaunchKernelGGL(merge_out, dim3(16384), dim3(256), 0, stream,
                       p.out, p.bwd);
  }
}